// Round 5
// baseline (427.779 us; speedup 1.0000x reference)
//
#include <hip/hip_runtime.h>
#include <hip/hip_bf16.h>

#define N_NODES 100000
#define N_EDGES 1000000
#define EMB 64
#define HID 64
#define VOCAB 128
#define N_GRAPHS 2048

#define BUCKET_NODES 256
#define NB ((N_NODES + BUCKET_NODES - 1) / BUCKET_NODES)   // 391
#define NSEG (NB * 8)                                      // 3128

#define BCASTF(v, l) __int_as_float(__builtin_amdgcn_readlane(__float_as_int(v), (l)))

// ---- precompute embW1l = emb @ W1l, embW1r = emb @ W1r  (128x64 each) ----
__global__ __launch_bounds__(256) void precompute_kernel(
    const float* __restrict__ emb, const float* __restrict__ W1l,
    const float* __restrict__ W1r,
    float* __restrict__ embW1l, float* __restrict__ embW1r)
{
    int wave = threadIdx.x >> 6, lane = threadIdx.x & 63;
    int v = blockIdx.x * 4 + wave;
    if (v >= VOCAB) return;
    float er = emb[v * 64 + lane];       // lane = d
    float al = 0.f, ar = 0.f;
#pragma unroll 8
    for (int d = 0; d < 64; ++d) {
        float e = BCASTF(er, d);
        al += e * W1l[d * 64 + lane];    // lane = o, L1-hot
        ar += e * W1r[d * 64 + lane];
    }
    embW1l[v * 64 + lane] = al;
    embW1r[v * 64 + lane] = ar;
}

// ---- stage A: per-(bucket, blockIdx&7) histogram --------------------------
// key must be identical in hist & scatter (same grid shape): blockIdx&7.
// blockIdx&7 ~ XCD (round-robin dispatch) => write locality in scatter.
__global__ __launch_bounds__(256) void hist_kernel(
    const int* __restrict__ dst, int* __restrict__ hist)
{
    int e = blockIdx.x * 256 + threadIdx.x;
    int k = blockIdx.x & 7;
    if (e < N_EDGES)
        atomicAdd(&hist[(dst[e] >> 8) * 8 + k], 1);
}

// ---- stage B: exclusive scan of NSEG counts -> base (and cursor copy) ----
__global__ __launch_bounds__(256) void scan_kernel(
    const int* __restrict__ hist, int* __restrict__ base,
    int* __restrict__ cursor)
{
    __shared__ int ssum[256];
    int t = threadIdx.x;
    const int CH = (NSEG + 255) / 256;    // 13
    int vals[CH];
    int mysum = 0;
#pragma unroll
    for (int i = 0; i < CH; ++i) {
        int idx = t * CH + i;
        int v = (idx < NSEG) ? hist[idx] : 0;
        vals[i] = v; mysum += v;
    }
    ssum[t] = mysum;
    __syncthreads();
    for (int off = 1; off < 256; off <<= 1) {
        int tmp = (t >= off) ? ssum[t - off] : 0;
        __syncthreads();
        ssum[t] += tmp;
        __syncthreads();
    }
    int run = ssum[t] - mysum;            // exclusive base of my chunk
#pragma unroll
    for (int i = 0; i < CH; ++i) {
        int idx = t * CH + i;
        if (idx < NSEG) { base[idx] = run; cursor[idx] = run; run += vals[i]; }
    }
    if (t == 255) base[NSEG] = run;       // == N_EDGES
}

// ---- stage C: scatter edges into bucket-segmented array (packed 4B) ------
__global__ __launch_bounds__(256) void scatter_kernel(
    const int* __restrict__ src, const int* __restrict__ dst,
    int* __restrict__ cursor, unsigned* __restrict__ edge8)
{
    int e = blockIdx.x * 256 + threadIdx.x;
    int k = blockIdx.x & 7;
    if (e < N_EDGES) {
        int d = dst[e];
        int pos = atomicAdd(&cursor[(d >> 8) * 8 + k], 1);
        edge8[pos] = (unsigned)src[e] | ((unsigned)(d & 255) << 17);  // src<2^17
    }
}

// ---- stage D: per-bucket CSR build (rowstart/deg/col), dense writes ------
__global__ __launch_bounds__(256) void csr_kernel(
    const unsigned* __restrict__ edge8, const int* __restrict__ base,
    int* __restrict__ row_start, int* __restrict__ deg, int* __restrict__ col)
{
    __shared__ int cnt[BUCKET_NODES];
    __shared__ int scn[BUCKET_NODES];
    int b = blockIdx.x;                   // NB blocks
    int t = threadIdx.x;
    int lo = base[b * 8], hi = base[(b + 1) * 8];
    cnt[t] = 0;
    __syncthreads();
    for (int i = lo + t; i < hi; i += 256)
        atomicAdd(&cnt[edge8[i] >> 17], 1);
    __syncthreads();
    int v = cnt[t];
    scn[t] = v;
    __syncthreads();
    for (int off = 1; off < 256; off <<= 1) {
        int tmp = (t >= off) ? scn[t - off] : 0;
        __syncthreads();
        scn[t] += tmp;
        __syncthreads();
    }
    int excl = scn[t] - v;
    int node = b * BUCKET_NODES + t;
    if (node < N_NODES) { row_start[node] = lo + excl; deg[node] = v; }
    cnt[t] = excl;                        // reuse as cursor
    __syncthreads();
    for (int i = lo + t; i < hi; i += 256) {
        unsigned e = edge8[i];
        int slot = atomicAdd(&cnt[e >> 17], 1);
        col[lo + slot] = (int)(e & 0x1FFFF);   // dense ~10 KB window
    }
}

// ---- graph boundaries (batch sorted) -------------------------------------
__global__ __launch_bounds__(256) void gstart_kernel(
    const int* __restrict__ batch, int* __restrict__ gstart)
{
    int i = blockIdx.x * 256 + threadIdx.x;
    if (i >= N_NODES) return;
    int bg = batch[i];
    int bp = (i == 0) ? -1 : batch[i - 1];
    for (int g = bp + 1; g <= bg; ++g) gstart[g] = i;
    if (i == N_NODES - 1)
        for (int g = bg + 1; g <= N_GRAPHS; ++g) gstart[g] = N_NODES;
}

// ---- layer 1: h1 = relu(mean_j(embW1l[x_j]) + b1 + embW1r[x_i]) ----
#define S1_NPW 8
__global__ __launch_bounds__(256) void sage1_kernel(
    const int* __restrict__ x, const float* __restrict__ embW1l,
    const float* __restrict__ embW1r, const float* __restrict__ b1,
    const int* __restrict__ row_start, const int* __restrict__ deg,
    const int* __restrict__ col, float* __restrict__ h1)
{
    __shared__ float elds[VOCAB * 64];   // 32 KB
    int t = threadIdx.x;
    for (int i = t * 4; i < VOCAB * 64; i += 1024)
        *(float4*)&elds[i] = *(const float4*)&embW1l[i];
    __syncthreads();

    int wave = t >> 6, lane = t & 63;
    int base_node = (blockIdx.x * 4 + wave) * S1_NPW;   // 3125*4*8 = 100000 exact
    float bias = b1[lane];

    for (int n = 0; n < S1_NPW; ++n) {
        int node = base_node + n;
        int rs = row_start[node];
        int dg = deg[node];
        int xn = x[node];
        float self = embW1r[xn * 64 + lane];            // 32 KB table, L1-hot
        int cidx = (lane < dg) ? col[rs + lane] : 0;
        int xv = (lane < dg) ? x[cidx] : 0;
        int dgc = (dg < 64) ? dg : 64;

        float s0 = 0.f, s1 = 0.f, s2 = 0.f, s3 = 0.f;
        int j = 0;
        for (; j + 4 <= dgc; j += 4) {
            int x0 = __builtin_amdgcn_readlane(xv, j + 0);
            int x1 = __builtin_amdgcn_readlane(xv, j + 1);
            int x2 = __builtin_amdgcn_readlane(xv, j + 2);
            int x3 = __builtin_amdgcn_readlane(xv, j + 3);
            s0 += elds[x0 * 64 + lane];
            s1 += elds[x1 * 64 + lane];
            s2 += elds[x2 * 64 + lane];
            s3 += elds[x3 * 64 + lane];
        }
        for (; j < dgc; ++j) {
            int x0 = __builtin_amdgcn_readlane(xv, j);
            s0 += elds[x0 * 64 + lane];
        }
        for (int k = 64; k < dg; ++k) {
            int c = col[rs + k];
            s0 += elds[x[c] * 64 + lane];
        }
        float mean = ((s0 + s1) + (s2 + s3)) / fmaxf((float)dg, 1.0f);
        h1[node * 64 + lane] = fmaxf(mean + bias + self, 0.f);
    }
}

// ---- dense transform: p = h1 @ W2l (in place over h1), q = h1 @ W2r ----
#define T_NPW 8
__global__ __launch_bounds__(256) void transform_kernel(
    float* __restrict__ h1p,            // in: h1, out: p (row-exact alias)
    const float* __restrict__ W2l, const float* __restrict__ W2r,
    float* __restrict__ q)
{
    __shared__ float2 w[HID * HID];     // (Wl[d][o], Wr[d][o]) interleaved, 32 KB
    __shared__ float ms[4][T_NPW][HID]; // 8 KB wave-private
    int t = threadIdx.x;
    for (int idx = t * 4; idx < HID * HID; idx += 1024) {
        float4 a = *(const float4*)(W2l + idx);
        float4 b = *(const float4*)(W2r + idx);
        w[idx + 0] = make_float2(a.x, b.x);
        w[idx + 1] = make_float2(a.y, b.y);
        w[idx + 2] = make_float2(a.z, b.z);
        w[idx + 3] = make_float2(a.w, b.w);
    }
    __syncthreads();

    int wave = t >> 6, lane = t & 63;
    int base_node = (blockIdx.x * 4 + wave) * T_NPW;    // exact cover

#pragma unroll
    for (int n = 0; n < T_NPW; ++n)
        ms[wave][n][lane] = h1p[(base_node + n) * 64 + lane];
    __builtin_amdgcn_wave_barrier();    // wave-private LDS; DS in-order per wave

    float accp[T_NPW], accq[T_NPW];
#pragma unroll
    for (int n = 0; n < T_NPW; ++n) { accp[n] = 0.f; accq[n] = 0.f; }

#pragma unroll 4
    for (int d = 0; d < HID; d += 4) {
        float2 w0 = w[(d + 0) * 64 + lane];
        float2 w1 = w[(d + 1) * 64 + lane];
        float2 w2 = w[(d + 2) * 64 + lane];
        float2 w3 = w[(d + 3) * 64 + lane];
#pragma unroll
        for (int n = 0; n < T_NPW; ++n) {
            float4 m = *(const float4*)&ms[wave][n][d];   // uniform broadcast
            accp[n] += m.x * w0.x + m.y * w1.x + m.z * w2.x + m.w * w3.x;
            accq[n] += m.x * w0.y + m.y * w1.y + m.z * w2.y + m.w * w3.y;
        }
    }
#pragma unroll
    for (int n = 0; n < T_NPW; ++n) {
        h1p[(base_node + n) * 64 + lane] = accp[n];   // p overwrites h1
        q[(base_node + n) * 64 + lane]   = accq[n];
    }
}

// ---- lean gather: h2 = relu(mean_j p_j + b2 + q_i); gsum[g] += h2@Wout ----
#define S2_NPW 8
__global__ __launch_bounds__(256, 8) void sage2_kernel(
    const float* __restrict__ p, const float* __restrict__ q,
    const int* __restrict__ row_start, const int* __restrict__ deg,
    const int* __restrict__ col, const float* __restrict__ b2,
    const float* __restrict__ Wout, const int* __restrict__ batch,
    float* __restrict__ gsum)
{
    int t = threadIdx.x;
    int wave = t >> 6, lane = t & 63;
    int base_node = (blockIdx.x * 4 + wave) * S2_NPW;   // exact cover
    float bias = b2[lane];
    float wo0 = Wout[lane * 2 + 0], wo1 = Wout[lane * 2 + 1];

    for (int n = 0; n < S2_NPW; ++n) {
        int node = base_node + n;
        int rs = row_start[node];       // wave-uniform -> scalar
        int dg = deg[node];
        int cidx = (lane < dg) ? col[rs + lane] : 0;
        int dgc = (dg < 64) ? dg : 64;

        float s0 = 0.f, s1 = 0.f, s2 = 0.f, s3 = 0.f,
              s4 = 0.f, s5 = 0.f, s6 = 0.f, s7 = 0.f;
        int j = 0;
        for (; j + 8 <= dgc; j += 8) {
            int i0 = __builtin_amdgcn_readlane(cidx, j + 0);
            int i1 = __builtin_amdgcn_readlane(cidx, j + 1);
            int i2 = __builtin_amdgcn_readlane(cidx, j + 2);
            int i3 = __builtin_amdgcn_readlane(cidx, j + 3);
            int i4 = __builtin_amdgcn_readlane(cidx, j + 4);
            int i5 = __builtin_amdgcn_readlane(cidx, j + 5);
            int i6 = __builtin_amdgcn_readlane(cidx, j + 6);
            int i7 = __builtin_amdgcn_readlane(cidx, j + 7);
            s0 += p[i0 * 64 + lane];  s1 += p[i1 * 64 + lane];
            s2 += p[i2 * 64 + lane];  s3 += p[i3 * 64 + lane];
            s4 += p[i4 * 64 + lane];  s5 += p[i5 * 64 + lane];
            s6 += p[i6 * 64 + lane];  s7 += p[i7 * 64 + lane];
        }
        for (; j + 4 <= dgc; j += 4) {
            int i0 = __builtin_amdgcn_readlane(cidx, j + 0);
            int i1 = __builtin_amdgcn_readlane(cidx, j + 1);
            int i2 = __builtin_amdgcn_readlane(cidx, j + 2);
            int i3 = __builtin_amdgcn_readlane(cidx, j + 3);
            s0 += p[i0 * 64 + lane];  s1 += p[i1 * 64 + lane];
            s2 += p[i2 * 64 + lane];  s3 += p[i3 * 64 + lane];
        }
        for (; j < dgc; ++j) {
            int i0 = __builtin_amdgcn_readlane(cidx, j);
            s0 += p[i0 * 64 + lane];
        }
        for (int k = 64; k < dg; ++k)
            s0 += p[col[rs + k] * 64 + lane];

        float sum = ((s0 + s1) + (s2 + s3)) + ((s4 + s5) + (s6 + s7));
        float mean = sum / fmaxf((float)dg, 1.0f);
        float h2 = fmaxf(mean + bias + q[node * 64 + lane], 0.f);

        float p0 = h2 * wo0, p1 = h2 * wo1;
#pragma unroll
        for (int off = 32; off > 0; off >>= 1) {
            p0 += __shfl_down(p0, off, 64);
            p1 += __shfl_down(p1, off, 64);
        }
        if (lane == 0) {
            int g = batch[node];
            atomicAdd(&gsum[g * 2 + 0], p0);
            atomicAdd(&gsum[g * 2 + 1], p1);
        }
    }
}

// ---------------- finalize: out = gsum/cnt + bout ----------------
__global__ __launch_bounds__(256) void finalize_kernel(
    const float* __restrict__ gsum, const int* __restrict__ gstart,
    const float* __restrict__ bout, float* __restrict__ out)
{
    int g = blockIdx.x * 256 + threadIdx.x;
    if (g >= N_GRAPHS) return;
    int cnt = gstart[g + 1] - gstart[g];
    float inv = 1.0f / fmaxf((float)cnt, 1.0f);
    out[g * 2 + 0] = gsum[g * 2 + 0] * inv + bout[0];
    out[g * 2 + 1] = gsum[g * 2 + 1] * inv + bout[1];
}

extern "C" void kernel_launch(void* const* d_in, const int* in_sizes, int n_in,
                              void* d_out, int out_size, void* d_ws, size_t ws_size,
                              hipStream_t stream) {
    const int*   x    = (const int*)  d_in[0];
    const int*   ei   = (const int*)  d_in[1];
    const int*   batch= (const int*)  d_in[2];
    const float* emb  = (const float*)d_in[3];
    const float* W1l  = (const float*)d_in[4];
    const float* b1   = (const float*)d_in[5];
    const float* W1r  = (const float*)d_in[6];
    const float* W2l  = (const float*)d_in[7];
    const float* b2   = (const float*)d_in[8];
    const float* W2r  = (const float*)d_in[9];
    const float* Wout = (const float*)d_in[10];
    const float* bout = (const float*)d_in[11];
    float* out = (float*)d_out;

    const int* src = ei;
    const int* dst = ei + N_EDGES;

    char* ws = (char*)d_ws;
    size_t off = 0;
    float*    h1p    = (float*)   (ws + off); off += (size_t)N_NODES * 64 * 4;  // h1 then p
    float*    q      = (float*)   (ws + off); off += (size_t)N_NODES * 64 * 4;
    float*    embW1l = (float*)   (ws + off); off += (size_t)VOCAB * 64 * 4;
    float*    embW1r = (float*)   (ws + off); off += (size_t)VOCAB * 64 * 4;
    int*      rowst  = (int*)     (ws + off); off += (size_t)N_NODES * 4;
    int*      deg    = (int*)     (ws + off); off += (size_t)N_NODES * 4;
    int*      col    = (int*)     (ws + off); off += (size_t)N_EDGES * 4;
    unsigned* edge8  = (unsigned*)(ws + off); off += (size_t)N_EDGES * 4;
    int*      base   = (int*)     (ws + off); off += (size_t)(NSEG + 1) * 4;
    int*      cursor = (int*)     (ws + off); off += (size_t)NSEG * 4;
    int*      gstart = (int*)     (ws + off); off += (size_t)(N_GRAPHS + 1) * 4;
    // contiguous zero region: hist | gsum
    int*      hist   = (int*)     (ws + off); off += (size_t)NSEG * 4;
    float*    gsum   = (float*)   (ws + off); off += (size_t)N_GRAPHS * 2 * 4;

    hipMemsetAsync(hist, 0, (size_t)NSEG * 4 + (size_t)N_GRAPHS * 2 * 4, stream);

    precompute_kernel<<<32, 256, 0, stream>>>(emb, W1l, W1r, embW1l, embW1r);
    hist_kernel<<<(N_EDGES + 255) / 256, 256, 0, stream>>>(dst, hist);
    scan_kernel<<<1, 256, 0, stream>>>(hist, base, cursor);
    scatter_kernel<<<(N_EDGES + 255) / 256, 256, 0, stream>>>(src, dst, cursor, edge8);
    gstart_kernel<<<(N_NODES + 255) / 256, 256, 0, stream>>>(batch, gstart);
    csr_kernel<<<NB, 256, 0, stream>>>(edge8, base, rowst, deg, col);
    sage1_kernel<<<N_NODES / (4 * S1_NPW), 256, 0, stream>>>(
        x, embW1l, embW1r, b1, rowst, deg, col, h1p);
    transform_kernel<<<N_NODES / (4 * T_NPW), 256, 0, stream>>>(h1p, W2l, W2r, q);
    sage2_kernel<<<N_NODES / (4 * S2_NPW), 256, 0, stream>>>(
        h1p, q, rowst, deg, col, b2, Wout, batch, gsum);
    finalize_kernel<<<(N_GRAPHS + 255) / 256, 256, 0, stream>>>(gsum, gstart, bout, out);
}

// Round 6
// 279.797 us; speedup vs baseline: 1.5289x; 1.5289x over previous
//
#include <hip/hip_runtime.h>
#include <hip/hip_bf16.h>

#define N_NODES 100000
#define N_EDGES 1000000
#define EMB 64
#define HID 64
#define VOCAB 128
#define N_GRAPHS 2048

#define CBUCKET 1024                                   // nodes per bucket
#define NBK ((N_NODES + CBUCKET - 1) / CBUCKET)        // 98
#define CHUNK 4096
#define SCAT_BLOCKS ((N_EDGES + CHUNK - 1) / CHUNK)    // 245

#define BCASTF(v, l) __int_as_float(__builtin_amdgcn_readlane(__float_as_int(v), (l)))

// ---- precompute embW1l = emb @ W1l, embW1r = emb @ W1r  (128x64 each) ----
__global__ __launch_bounds__(256) void precompute_kernel(
    const float* __restrict__ emb, const float* __restrict__ W1l,
    const float* __restrict__ W1r,
    float* __restrict__ embW1l, float* __restrict__ embW1r)
{
    int wave = threadIdx.x >> 6, lane = threadIdx.x & 63;
    int v = blockIdx.x * 4 + wave;
    if (v >= VOCAB) return;
    float er = emb[v * 64 + lane];       // lane = d
    float al = 0.f, ar = 0.f;
#pragma unroll 8
    for (int d = 0; d < 64; ++d) {
        float e = BCASTF(er, d);
        al += e * W1l[d * 64 + lane];    // lane = o, L1-hot
        ar += e * W1r[d * 64 + lane];
    }
    embW1l[v * 64 + lane] = al;
    embW1r[v * 64 + lane] = ar;
}

// ---- stage A: per-bucket totals (LDS-reduced, 98 global atomics/block) ----
__global__ __launch_bounds__(256) void hist_kernel(
    const int* __restrict__ dst, int* __restrict__ hist)
{
    __shared__ int hl[NBK];
    int t = threadIdx.x;
    if (t < NBK) hl[t] = 0;
    __syncthreads();
    int e0 = blockIdx.x * CHUNK;
    int e1 = min(e0 + CHUNK, N_EDGES);
    for (int e = e0 + t; e < e1; e += 256)
        atomicAdd(&hl[dst[e] >> 10], 1);
    __syncthreads();
    if (t < NBK && hl[t]) atomicAdd(&hist[t], hl[t]);
}

// ---- stage B: exclusive scan of NBK counts -> base + cursor ----
__global__ __launch_bounds__(128) void scan_kernel(
    const int* __restrict__ hist, int* __restrict__ base,
    int* __restrict__ cursor)
{
    __shared__ int s[128];
    int t = threadIdx.x;
    int v = (t < NBK) ? hist[t] : 0;
    s[t] = v;
    __syncthreads();
    for (int off = 1; off < 128; off <<= 1) {
        int tmp = (t >= off) ? s[t - off] : 0;
        __syncthreads();
        s[t] += tmp;
        __syncthreads();
    }
    if (t < NBK) { int b = s[t] - v; base[t] = b; cursor[t] = b; }
    if (t == 127) base[NBK] = s[127];      // == N_EDGES
}

// ---- stage C: scatter with per-(block,bucket) run reservation ----
// Each block reserves ONE contiguous run per bucket (~42 edges) and writes it
// densely -> single-writer cache lines, no cross-XCD line sharing.
__global__ __launch_bounds__(256) void scatter_kernel(
    const int* __restrict__ src, const int* __restrict__ dst,
    int* __restrict__ cursor, unsigned* __restrict__ edge8)
{
    __shared__ int bcnt[NBK];
    __shared__ int bbase[NBK];
    int t = threadIdx.x;
    if (t < NBK) bcnt[t] = 0;
    __syncthreads();
    int e0 = blockIdx.x * CHUNK;
    int e1 = min(e0 + CHUNK, N_EDGES);
    for (int e = e0 + t; e < e1; e += 256)
        atomicAdd(&bcnt[dst[e] >> 10], 1);
    __syncthreads();
    if (t < NBK) {
        int c = bcnt[t];
        bbase[t] = c ? atomicAdd(&cursor[t], c) : 0;
        bcnt[t] = 0;                        // reuse as local cursor
    }
    __syncthreads();
    for (int e = e0 + t; e < e1; e += 256) {
        int d = dst[e];
        int k = d >> 10;
        int off = atomicAdd(&bcnt[k], 1);
        edge8[bbase[k] + off] = (unsigned)src[e] | ((unsigned)(d & 1023) << 17);
    }
}

// ---- stage D: per-bucket CSR build (rowstart/deg/col), dense writes ------
__global__ __launch_bounds__(256) void csr_kernel(
    const unsigned* __restrict__ edge8, const int* __restrict__ base,
    int* __restrict__ row_start, int* __restrict__ deg, int* __restrict__ col)
{
    __shared__ int cnt[CBUCKET];
    __shared__ int ssum[256];
    int b = blockIdx.x;                   // NBK blocks
    int t = threadIdx.x;
    int lo = base[b], hi = base[b + 1];
    for (int i = t; i < CBUCKET; i += 256) cnt[i] = 0;
    __syncthreads();
    for (int i = lo + t; i < hi; i += 256)
        atomicAdd(&cnt[edge8[i] >> 17], 1);
    __syncthreads();
    int v[4]; int sum = 0;
#pragma unroll
    for (int i = 0; i < 4; ++i) { v[i] = cnt[t * 4 + i]; sum += v[i]; }
    ssum[t] = sum;
    __syncthreads();
    for (int off = 1; off < 256; off <<= 1) {
        int tmp = (t >= off) ? ssum[t - off] : 0;
        __syncthreads();
        ssum[t] += tmp;
        __syncthreads();
    }
    int run = ssum[t] - sum;
    int ex0 = run, ex1 = ex0 + v[0], ex2 = ex1 + v[1], ex3 = ex2 + v[2];
    int node = b * CBUCKET + t * 4;
    if (node + 3 < N_NODES) {
        *(int4*)&row_start[node] = make_int4(lo + ex0, lo + ex1, lo + ex2, lo + ex3);
        *(int4*)&deg[node]       = make_int4(v[0], v[1], v[2], v[3]);
    } else {
        int ex[4] = {ex0, ex1, ex2, ex3};
        for (int i = 0; i < 4; ++i)
            if (node + i < N_NODES) { row_start[node + i] = lo + ex[i]; deg[node + i] = v[i]; }
    }
    cnt[t * 4 + 0] = ex0; cnt[t * 4 + 1] = ex1;       // reuse as cursors
    cnt[t * 4 + 2] = ex2; cnt[t * 4 + 3] = ex3;
    __syncthreads();
    for (int i = lo + t; i < hi; i += 256) {
        unsigned e = edge8[i];
        int slot = atomicAdd(&cnt[e >> 17], 1);
        col[lo + slot] = (int)(e & 0x1FFFF);          // dense ~40 KB window
    }
}

// ---- graph boundaries (batch sorted) -------------------------------------
__global__ __launch_bounds__(256) void gstart_kernel(
    const int* __restrict__ batch, int* __restrict__ gstart)
{
    int i = blockIdx.x * 256 + threadIdx.x;
    if (i >= N_NODES) return;
    int bg = batch[i];
    int bp = (i == 0) ? -1 : batch[i - 1];
    for (int g = bp + 1; g <= bg; ++g) gstart[g] = i;
    if (i == N_NODES - 1)
        for (int g = bg + 1; g <= N_GRAPHS; ++g) gstart[g] = N_NODES;
}

// ---- layer 1: h1 = relu(mean_j(embW1l[x_j]) + b1 + embW1r[x_i]) ----
#define S1_NPW 8
__global__ __launch_bounds__(256) void sage1_kernel(
    const int* __restrict__ x, const float* __restrict__ embW1l,
    const float* __restrict__ embW1r, const float* __restrict__ b1,
    const int* __restrict__ row_start, const int* __restrict__ deg,
    const int* __restrict__ col, float* __restrict__ h1)
{
    __shared__ float elds[VOCAB * 64];   // 32 KB
    int t = threadIdx.x;
    for (int i = t * 4; i < VOCAB * 64; i += 1024)
        *(float4*)&elds[i] = *(const float4*)&embW1l[i];
    __syncthreads();

    int wave = t >> 6, lane = t & 63;
    int base_node = (blockIdx.x * 4 + wave) * S1_NPW;   // 3125*4*8 = 100000 exact
    float bias = b1[lane];

    for (int n = 0; n < S1_NPW; ++n) {
        int node = base_node + n;
        int rs = row_start[node];
        int dg = deg[node];
        int xn = x[node];
        float self = embW1r[xn * 64 + lane];            // 32 KB table, L1-hot
        int cidx = (lane < dg) ? col[rs + lane] : 0;
        int xv = (lane < dg) ? x[cidx] : 0;
        int dgc = (dg < 64) ? dg : 64;

        float s0 = 0.f, s1 = 0.f, s2 = 0.f, s3 = 0.f;
        int j = 0;
        for (; j + 4 <= dgc; j += 4) {
            int x0 = __builtin_amdgcn_readlane(xv, j + 0);
            int x1 = __builtin_amdgcn_readlane(xv, j + 1);
            int x2 = __builtin_amdgcn_readlane(xv, j + 2);
            int x3 = __builtin_amdgcn_readlane(xv, j + 3);
            s0 += elds[x0 * 64 + lane];
            s1 += elds[x1 * 64 + lane];
            s2 += elds[x2 * 64 + lane];
            s3 += elds[x3 * 64 + lane];
        }
        for (; j < dgc; ++j) {
            int x0 = __builtin_amdgcn_readlane(xv, j);
            s0 += elds[x0 * 64 + lane];
        }
        for (int k = 64; k < dg; ++k) {
            int c = col[rs + k];
            s0 += elds[x[c] * 64 + lane];
        }
        float mean = ((s0 + s1) + (s2 + s3)) / fmaxf((float)dg, 1.0f);
        h1[node * 64 + lane] = fmaxf(mean + bias + self, 0.f);
    }
}

// ---- dense transform: p = h1 @ W2l (in place over h1), q = h1 @ W2r ----
#define T_NPW 8
__global__ __launch_bounds__(256) void transform_kernel(
    float* __restrict__ h1p,            // in: h1, out: p (row-exact alias)
    const float* __restrict__ W2l, const float* __restrict__ W2r,
    float* __restrict__ q)
{
    __shared__ float2 w[HID * HID];     // (Wl[d][o], Wr[d][o]) interleaved, 32 KB
    __shared__ float ms[4][T_NPW][HID]; // 8 KB wave-private
    int t = threadIdx.x;
    for (int idx = t * 4; idx < HID * HID; idx += 1024) {
        float4 a = *(const float4*)(W2l + idx);
        float4 b = *(const float4*)(W2r + idx);
        w[idx + 0] = make_float2(a.x, b.x);
        w[idx + 1] = make_float2(a.y, b.y);
        w[idx + 2] = make_float2(a.z, b.z);
        w[idx + 3] = make_float2(a.w, b.w);
    }
    __syncthreads();

    int wave = t >> 6, lane = t & 63;
    int base_node = (blockIdx.x * 4 + wave) * T_NPW;    // exact cover

#pragma unroll
    for (int n = 0; n < T_NPW; ++n)
        ms[wave][n][lane] = h1p[(base_node + n) * 64 + lane];
    __builtin_amdgcn_wave_barrier();    // wave-private LDS; DS in-order per wave

    float accp[T_NPW], accq[T_NPW];
#pragma unroll
    for (int n = 0; n < T_NPW; ++n) { accp[n] = 0.f; accq[n] = 0.f; }

#pragma unroll 4
    for (int d = 0; d < HID; d += 4) {
        float2 w0 = w[(d + 0) * 64 + lane];
        float2 w1 = w[(d + 1) * 64 + lane];
        float2 w2 = w[(d + 2) * 64 + lane];
        float2 w3 = w[(d + 3) * 64 + lane];
#pragma unroll
        for (int n = 0; n < T_NPW; ++n) {
            float4 m = *(const float4*)&ms[wave][n][d];   // uniform broadcast
            accp[n] += m.x * w0.x + m.y * w1.x + m.z * w2.x + m.w * w3.x;
            accq[n] += m.x * w0.y + m.y * w1.y + m.z * w2.y + m.w * w3.y;
        }
    }
#pragma unroll
    for (int n = 0; n < T_NPW; ++n) {
        h1p[(base_node + n) * 64 + lane] = accp[n];   // p overwrites h1
        q[(base_node + n) * 64 + lane]   = accq[n];
    }
}

// ---- lean gather: h2 = relu(mean_j p_j + b2 + q_i); gsum[g] += h2@Wout ----
#define S2_NPW 8
__global__ __launch_bounds__(256, 8) void sage2_kernel(
    const float* __restrict__ p, const float* __restrict__ q,
    const int* __restrict__ row_start, const int* __restrict__ deg,
    const int* __restrict__ col, const float* __restrict__ b2,
    const float* __restrict__ Wout, const int* __restrict__ batch,
    float* __restrict__ gsum)
{
    int t = threadIdx.x;
    int wave = t >> 6, lane = t & 63;
    int base_node = (blockIdx.x * 4 + wave) * S2_NPW;   // exact cover
    float bias = b2[lane];
    float wo0 = Wout[lane * 2 + 0], wo1 = Wout[lane * 2 + 1];

    for (int n = 0; n < S2_NPW; ++n) {
        int node = base_node + n;
        int rs = row_start[node];       // wave-uniform -> scalar
        int dg = deg[node];
        int cidx = (lane < dg) ? col[rs + lane] : 0;
        int dgc = (dg < 64) ? dg : 64;

        float s0 = 0.f, s1 = 0.f, s2 = 0.f, s3 = 0.f,
              s4 = 0.f, s5 = 0.f, s6 = 0.f, s7 = 0.f;
        int j = 0;
        for (; j + 8 <= dgc; j += 8) {
            int i0 = __builtin_amdgcn_readlane(cidx, j + 0);
            int i1 = __builtin_amdgcn_readlane(cidx, j + 1);
            int i2 = __builtin_amdgcn_readlane(cidx, j + 2);
            int i3 = __builtin_amdgcn_readlane(cidx, j + 3);
            int i4 = __builtin_amdgcn_readlane(cidx, j + 4);
            int i5 = __builtin_amdgcn_readlane(cidx, j + 5);
            int i6 = __builtin_amdgcn_readlane(cidx, j + 6);
            int i7 = __builtin_amdgcn_readlane(cidx, j + 7);
            s0 += p[i0 * 64 + lane];  s1 += p[i1 * 64 + lane];
            s2 += p[i2 * 64 + lane];  s3 += p[i3 * 64 + lane];
            s4 += p[i4 * 64 + lane];  s5 += p[i5 * 64 + lane];
            s6 += p[i6 * 64 + lane];  s7 += p[i7 * 64 + lane];
        }
        for (; j + 4 <= dgc; j += 4) {
            int i0 = __builtin_amdgcn_readlane(cidx, j + 0);
            int i1 = __builtin_amdgcn_readlane(cidx, j + 1);
            int i2 = __builtin_amdgcn_readlane(cidx, j + 2);
            int i3 = __builtin_amdgcn_readlane(cidx, j + 3);
            s0 += p[i0 * 64 + lane];  s1 += p[i1 * 64 + lane];
            s2 += p[i2 * 64 + lane];  s3 += p[i3 * 64 + lane];
        }
        for (; j < dgc; ++j) {
            int i0 = __builtin_amdgcn_readlane(cidx, j);
            s0 += p[i0 * 64 + lane];
        }
        for (int k = 64; k < dg; ++k)
            s0 += p[col[rs + k] * 64 + lane];

        float sum = ((s0 + s1) + (s2 + s3)) + ((s4 + s5) + (s6 + s7));
        float mean = sum / fmaxf((float)dg, 1.0f);
        float h2 = fmaxf(mean + bias + q[node * 64 + lane], 0.f);

        float p0 = h2 * wo0, p1 = h2 * wo1;
#pragma unroll
        for (int off = 32; off > 0; off >>= 1) {
            p0 += __shfl_down(p0, off, 64);
            p1 += __shfl_down(p1, off, 64);
        }
        if (lane == 0) {
            int g = batch[node];
            atomicAdd(&gsum[g * 2 + 0], p0);
            atomicAdd(&gsum[g * 2 + 1], p1);
        }
    }
}

// ---------------- finalize: out = gsum/cnt + bout ----------------
__global__ __launch_bounds__(256) void finalize_kernel(
    const float* __restrict__ gsum, const int* __restrict__ gstart,
    const float* __restrict__ bout, float* __restrict__ out)
{
    int g = blockIdx.x * 256 + threadIdx.x;
    if (g >= N_GRAPHS) return;
    int cnt = gstart[g + 1] - gstart[g];
    float inv = 1.0f / fmaxf((float)cnt, 1.0f);
    out[g * 2 + 0] = gsum[g * 2 + 0] * inv + bout[0];
    out[g * 2 + 1] = gsum[g * 2 + 1] * inv + bout[1];
}

extern "C" void kernel_launch(void* const* d_in, const int* in_sizes, int n_in,
                              void* d_out, int out_size, void* d_ws, size_t ws_size,
                              hipStream_t stream) {
    const int*   x    = (const int*)  d_in[0];
    const int*   ei   = (const int*)  d_in[1];
    const int*   batch= (const int*)  d_in[2];
    const float* emb  = (const float*)d_in[3];
    const float* W1l  = (const float*)d_in[4];
    const float* b1   = (const float*)d_in[5];
    const float* W1r  = (const float*)d_in[6];
    const float* W2l  = (const float*)d_in[7];
    const float* b2   = (const float*)d_in[8];
    const float* W2r  = (const float*)d_in[9];
    const float* Wout = (const float*)d_in[10];
    const float* bout = (const float*)d_in[11];
    float* out = (float*)d_out;

    const int* src = ei;
    const int* dst = ei + N_EDGES;

    char* ws = (char*)d_ws;
    size_t off = 0;
    float*    h1p    = (float*)   (ws + off); off += (size_t)N_NODES * 64 * 4;  // h1 then p
    float*    q      = (float*)   (ws + off); off += (size_t)N_NODES * 64 * 4;
    float*    embW1l = (float*)   (ws + off); off += (size_t)VOCAB * 64 * 4;
    float*    embW1r = (float*)   (ws + off); off += (size_t)VOCAB * 64 * 4;
    int*      rowst  = (int*)     (ws + off); off += (size_t)N_NODES * 4;
    int*      deg    = (int*)     (ws + off); off += (size_t)N_NODES * 4;
    int*      col    = (int*)     (ws + off); off += (size_t)N_EDGES * 4;
    unsigned* edge8  = (unsigned*)(ws + off); off += (size_t)N_EDGES * 4;
    int*      base   = (int*)     (ws + off); off += (size_t)(NBK + 1) * 4;
    int*      cursor = (int*)     (ws + off); off += (size_t)NBK * 4;
    int*      gstart = (int*)     (ws + off); off += (size_t)(N_GRAPHS + 1) * 4;
    // contiguous zero region: hist | gsum
    int*      hist   = (int*)     (ws + off); off += (size_t)NBK * 4;
    float*    gsum   = (float*)   (ws + off); off += (size_t)N_GRAPHS * 2 * 4;

    hipMemsetAsync(hist, 0, (size_t)NBK * 4 + (size_t)N_GRAPHS * 2 * 4, stream);

    precompute_kernel<<<32, 256, 0, stream>>>(emb, W1l, W1r, embW1l, embW1r);
    hist_kernel<<<SCAT_BLOCKS, 256, 0, stream>>>(dst, hist);
    scan_kernel<<<1, 128, 0, stream>>>(hist, base, cursor);
    scatter_kernel<<<SCAT_BLOCKS, 256, 0, stream>>>(src, dst, cursor, edge8);
    gstart_kernel<<<(N_NODES + 255) / 256, 256, 0, stream>>>(batch, gstart);
    csr_kernel<<<NBK, 256, 0, stream>>>(edge8, base, rowst, deg, col);
    sage1_kernel<<<N_NODES / (4 * S1_NPW), 256, 0, stream>>>(
        x, embW1l, embW1r, b1, rowst, deg, col, h1p);
    transform_kernel<<<N_NODES / (4 * T_NPW), 256, 0, stream>>>(h1p, W2l, W2r, q);
    sage2_kernel<<<N_NODES / (4 * S2_NPW), 256, 0, stream>>>(
        h1p, q, rowst, deg, col, b2, Wout, batch, gsum);
    finalize_kernel<<<(N_GRAPHS + 255) / 256, 256, 0, stream>>>(gsum, gstart, bout, out);
}

// Round 7
// 248.057 us; speedup vs baseline: 1.7245x; 1.1280x over previous
//
#include <hip/hip_runtime.h>
#include <hip/hip_bf16.h>

#define N_NODES 100000
#define N_EDGES 1000000
#define EMB 64
#define HID 64
#define VOCAB 128
#define N_GRAPHS 2048

#define CBUCKET 1024                                   // nodes per bucket
#define NBK ((N_NODES + CBUCKET - 1) / CBUCKET)        // 98
#define CAP 16384                                      // slots per bucket (E[cnt]=10204, 60σ margin)
#define CHUNK 4096
#define SCAT_BLOCKS ((N_EDGES + CHUNK - 1) / CHUNK)    // 245

#define BCASTF(v, l) __int_as_float(__builtin_amdgcn_readlane(__float_as_int(v), (l)))

__device__ __forceinline__ float bf2f(unsigned short u) {
    return __uint_as_float((unsigned)u << 16);
}

// ---- init: cursor[k] = k*CAP, gsum = 0 ----
__global__ __launch_bounds__(256) void init_kernel(
    int* __restrict__ cursor, float* __restrict__ gsum)
{
    int t = blockIdx.x * 256 + threadIdx.x;
    if (t < NBK) cursor[t] = t * CAP;
    if (t < N_GRAPHS * 2) gsum[t] = 0.f;
}

// ---- precompute embW1l = emb @ W1l, embW1r = emb @ W1r  (128x64 each) ----
__global__ __launch_bounds__(256) void precompute_kernel(
    const float* __restrict__ emb, const float* __restrict__ W1l,
    const float* __restrict__ W1r,
    float* __restrict__ embW1l, float* __restrict__ embW1r)
{
    int wave = threadIdx.x >> 6, lane = threadIdx.x & 63;
    int v = blockIdx.x * 4 + wave;
    if (v >= VOCAB) return;
    float er = emb[v * 64 + lane];       // lane = d
    float al = 0.f, ar = 0.f;
#pragma unroll 8
    for (int d = 0; d < 64; ++d) {
        float e = BCASTF(er, d);
        al += e * W1l[d * 64 + lane];    // lane = o, L1-hot
        ar += e * W1r[d * 64 + lane];
    }
    embW1l[v * 64 + lane] = al;
    embW1r[v * 64 + lane] = ar;
}

// ---- scatter: LDS-staged chunk, per-(block,bucket) run reservation ----
// fixed-capacity buckets (base = k*CAP) -> no hist/scan prepass needed
__global__ __launch_bounds__(256) void scatter_kernel(
    const int* __restrict__ src, const int* __restrict__ dst,
    int* __restrict__ cursor, unsigned* __restrict__ edge8)
{
    __shared__ unsigned earr[CHUNK];        // 16 KB packed payload
    __shared__ unsigned char karr[CHUNK];   // 4 KB bucket key
    __shared__ int bcnt[NBK];
    __shared__ int bbase[NBK];
    int t = threadIdx.x;
    if (t < NBK) bcnt[t] = 0;
    __syncthreads();
    int e0 = blockIdx.x * CHUNK;
    int n = min(e0 + CHUNK, N_EDGES) - e0;
    for (int i = t; i < n; i += 256) {
        int d = dst[e0 + i];
        int s = src[e0 + i];
        int k = d >> 10;
        earr[i] = (unsigned)s | ((unsigned)(d & 1023) << 17);   // src < 2^17
        karr[i] = (unsigned char)k;
        atomicAdd(&bcnt[k], 1);
    }
    __syncthreads();
    if (t < NBK) {
        int c = bcnt[t];
        bbase[t] = c ? atomicAdd(&cursor[t], c) : 0;
        bcnt[t] = 0;                        // reuse as local cursor
    }
    __syncthreads();
    for (int i = t; i < n; i += 256) {
        int k = karr[i];
        int off = atomicAdd(&bcnt[k], 1);
        edge8[bbase[k] + off] = earr[i];    // dense single-writer runs
    }
}

// ---- per-bucket CSR build (rowstart/deg/col), dense writes ------
__global__ __launch_bounds__(256) void csr_kernel(
    const unsigned* __restrict__ edge8, const int* __restrict__ cursor,
    int* __restrict__ row_start, int* __restrict__ deg, int* __restrict__ col)
{
    __shared__ int cnt[CBUCKET];
    __shared__ int ssum[256];
    int b = blockIdx.x;                   // NBK blocks
    int t = threadIdx.x;
    int lo = b * CAP, hi = cursor[b];     // cursor holds final fill level
    for (int i = t; i < CBUCKET; i += 256) cnt[i] = 0;
    __syncthreads();
    for (int i = lo + t; i < hi; i += 256)
        atomicAdd(&cnt[edge8[i] >> 17], 1);
    __syncthreads();
    int v[4]; int sum = 0;
#pragma unroll
    for (int i = 0; i < 4; ++i) { v[i] = cnt[t * 4 + i]; sum += v[i]; }
    ssum[t] = sum;
    __syncthreads();
    for (int off = 1; off < 256; off <<= 1) {
        int tmp = (t >= off) ? ssum[t - off] : 0;
        __syncthreads();
        ssum[t] += tmp;
        __syncthreads();
    }
    int run = ssum[t] - sum;
    int ex0 = run, ex1 = ex0 + v[0], ex2 = ex1 + v[1], ex3 = ex2 + v[2];
    int node = b * CBUCKET + t * 4;
    if (node + 3 < N_NODES) {
        *(int4*)&row_start[node] = make_int4(lo + ex0, lo + ex1, lo + ex2, lo + ex3);
        *(int4*)&deg[node]       = make_int4(v[0], v[1], v[2], v[3]);
    } else {
        int ex[4] = {ex0, ex1, ex2, ex3};
        for (int i = 0; i < 4; ++i)
            if (node + i < N_NODES) { row_start[node + i] = lo + ex[i]; deg[node + i] = v[i]; }
    }
    cnt[t * 4 + 0] = ex0; cnt[t * 4 + 1] = ex1;       // reuse as cursors
    cnt[t * 4 + 2] = ex2; cnt[t * 4 + 3] = ex3;
    __syncthreads();
    for (int i = lo + t; i < hi; i += 256) {
        unsigned e = edge8[i];
        int slot = atomicAdd(&cnt[e >> 17], 1);
        col[lo + slot] = (int)(e & 0x1FFFF);          // dense ~40 KB window
    }
}

// ---- graph boundaries (batch sorted) -------------------------------------
__global__ __launch_bounds__(256) void gstart_kernel(
    const int* __restrict__ batch, int* __restrict__ gstart)
{
    int i = blockIdx.x * 256 + threadIdx.x;
    if (i >= N_NODES) return;
    int bg = batch[i];
    int bp = (i == 0) ? -1 : batch[i - 1];
    for (int g = bp + 1; g <= bg; ++g) gstart[g] = i;
    if (i == N_NODES - 1)
        for (int g = bg + 1; g <= N_GRAPHS; ++g) gstart[g] = N_NODES;
}

// ---- fused layer1 + layer2 dense transform:
//   h1 = relu(mean_j(embW1l[x_j]) + b1 + embW1r[x_i])   (phase A, LDS table)
//   p = h1@W2l (bf16), q = h1@W2r (bf16)                (phase B, LDS restaged)
#define S1_NPW 8
__global__ __launch_bounds__(256) void sage1_kernel(
    const int* __restrict__ x, const float* __restrict__ embW1l,
    const float* __restrict__ embW1r, const float* __restrict__ b1,
    const int* __restrict__ row_start, const int* __restrict__ deg,
    const int* __restrict__ col,
    const float* __restrict__ W2l, const float* __restrict__ W2r,
    __hip_bfloat16* __restrict__ p16, __hip_bfloat16* __restrict__ q16)
{
    __shared__ float sw[VOCAB * 64];        // 32 KB: phase A = embW1l, phase B = W2 float2
    __shared__ float msbuf[4][S1_NPW][64];  // 8 KB wave-private h1 rows
    int t = threadIdx.x;
    for (int i = t * 4; i < VOCAB * 64; i += 1024)
        *(float4*)&sw[i] = *(const float4*)&embW1l[i];
    __syncthreads();

    int wave = t >> 6, lane = t & 63;
    int base_node = (blockIdx.x * 4 + wave) * S1_NPW;   // 3125*32 = 100000 exact
    float bias = b1[lane];

    // ---- phase A: layer-1 aggregate from LDS table ----
    for (int n = 0; n < S1_NPW; ++n) {
        int node = base_node + n;
        int rs = row_start[node];
        int dg = deg[node];
        int xn = x[node];
        float self = embW1r[xn * 64 + lane];            // 32 KB table, L1-hot
        int cidx = (lane < dg) ? col[rs + lane] : 0;
        int xv = (lane < dg) ? x[cidx] : 0;
        int dgc = (dg < 64) ? dg : 64;

        float s0 = 0.f, s1 = 0.f, s2 = 0.f, s3 = 0.f;
        int j = 0;
        for (; j + 4 <= dgc; j += 4) {
            int x0 = __builtin_amdgcn_readlane(xv, j + 0);
            int x1 = __builtin_amdgcn_readlane(xv, j + 1);
            int x2 = __builtin_amdgcn_readlane(xv, j + 2);
            int x3 = __builtin_amdgcn_readlane(xv, j + 3);
            s0 += sw[x0 * 64 + lane];
            s1 += sw[x1 * 64 + lane];
            s2 += sw[x2 * 64 + lane];
            s3 += sw[x3 * 64 + lane];
        }
        for (; j < dgc; ++j) {
            int x0 = __builtin_amdgcn_readlane(xv, j);
            s0 += sw[x0 * 64 + lane];
        }
        for (int k = 64; k < dg; ++k) {
            int c = col[rs + k];
            s0 += sw[x[c] * 64 + lane];
        }
        float mean = ((s0 + s1) + (s2 + s3)) / fmaxf((float)dg, 1.0f);
        msbuf[wave][n][lane] = fmaxf(mean + bias + self, 0.f);
    }
    __syncthreads();

    // ---- restage: W2l/W2r interleaved into the same 32 KB ----
    float2* w2 = (float2*)sw;
    for (int idx = t * 4; idx < HID * HID; idx += 1024) {
        float4 a = *(const float4*)(W2l + idx);
        float4 b = *(const float4*)(W2r + idx);
        w2[idx + 0] = make_float2(a.x, b.x);
        w2[idx + 1] = make_float2(a.y, b.y);
        w2[idx + 2] = make_float2(a.z, b.z);
        w2[idx + 3] = make_float2(a.w, b.w);
    }
    __syncthreads();

    // ---- phase B: p = h1@W2l, q = h1@W2r ----
    float accp[S1_NPW], accq[S1_NPW];
#pragma unroll
    for (int n = 0; n < S1_NPW; ++n) { accp[n] = 0.f; accq[n] = 0.f; }
#pragma unroll 4
    for (int d = 0; d < HID; d += 4) {
        float2 w0 = w2[(d + 0) * 64 + lane];
        float2 w1 = w2[(d + 1) * 64 + lane];
        float2 w2v = w2[(d + 2) * 64 + lane];
        float2 w3 = w2[(d + 3) * 64 + lane];
#pragma unroll
        for (int n = 0; n < S1_NPW; ++n) {
            float4 m = *(const float4*)&msbuf[wave][n][d];   // uniform broadcast
            accp[n] += m.x * w0.x + m.y * w1.x + m.z * w2v.x + m.w * w3.x;
            accq[n] += m.x * w0.y + m.y * w1.y + m.z * w2v.y + m.w * w3.y;
        }
    }
#pragma unroll
    for (int n = 0; n < S1_NPW; ++n) {
        p16[(base_node + n) * 64 + lane] = __float2bfloat16(accp[n]);
        q16[(base_node + n) * 64 + lane] = __float2bfloat16(accq[n]);
    }
}

// ---- lean gather: h2 = relu(mean_j p_j + b2 + q_i); gsum[g] += h2@Wout ----
#define S2_NPW 8
__global__ __launch_bounds__(256, 8) void sage2_kernel(
    const unsigned short* __restrict__ p, const unsigned short* __restrict__ q,
    const int* __restrict__ row_start, const int* __restrict__ deg,
    const int* __restrict__ col, const float* __restrict__ b2,
    const float* __restrict__ Wout, const int* __restrict__ batch,
    float* __restrict__ gsum)
{
    int t = threadIdx.x;
    int wave = t >> 6, lane = t & 63;
    int base_node = (blockIdx.x * 4 + wave) * S2_NPW;   // exact cover
    float bias = b2[lane];
    float wo0 = Wout[lane * 2 + 0], wo1 = Wout[lane * 2 + 1];

    for (int n = 0; n < S2_NPW; ++n) {
        int node = base_node + n;
        int rs = row_start[node];       // wave-uniform -> scalar
        int dg = deg[node];
        int cidx = (lane < dg) ? col[rs + lane] : 0;
        int dgc = (dg < 64) ? dg : 64;

        float s0 = 0.f, s1 = 0.f, s2 = 0.f, s3 = 0.f,
              s4 = 0.f, s5 = 0.f, s6 = 0.f, s7 = 0.f;
        int j = 0;
        for (; j + 8 <= dgc; j += 8) {
            int i0 = __builtin_amdgcn_readlane(cidx, j + 0);
            int i1 = __builtin_amdgcn_readlane(cidx, j + 1);
            int i2 = __builtin_amdgcn_readlane(cidx, j + 2);
            int i3 = __builtin_amdgcn_readlane(cidx, j + 3);
            int i4 = __builtin_amdgcn_readlane(cidx, j + 4);
            int i5 = __builtin_amdgcn_readlane(cidx, j + 5);
            int i6 = __builtin_amdgcn_readlane(cidx, j + 6);
            int i7 = __builtin_amdgcn_readlane(cidx, j + 7);
            s0 += bf2f(p[i0 * 64 + lane]);  s1 += bf2f(p[i1 * 64 + lane]);
            s2 += bf2f(p[i2 * 64 + lane]);  s3 += bf2f(p[i3 * 64 + lane]);
            s4 += bf2f(p[i4 * 64 + lane]);  s5 += bf2f(p[i5 * 64 + lane]);
            s6 += bf2f(p[i6 * 64 + lane]);  s7 += bf2f(p[i7 * 64 + lane]);
        }
        for (; j + 4 <= dgc; j += 4) {
            int i0 = __builtin_amdgcn_readlane(cidx, j + 0);
            int i1 = __builtin_amdgcn_readlane(cidx, j + 1);
            int i2 = __builtin_amdgcn_readlane(cidx, j + 2);
            int i3 = __builtin_amdgcn_readlane(cidx, j + 3);
            s0 += bf2f(p[i0 * 64 + lane]);  s1 += bf2f(p[i1 * 64 + lane]);
            s2 += bf2f(p[i2 * 64 + lane]);  s3 += bf2f(p[i3 * 64 + lane]);
        }
        for (; j < dgc; ++j) {
            int i0 = __builtin_amdgcn_readlane(cidx, j);
            s0 += bf2f(p[i0 * 64 + lane]);
        }
        for (int k = 64; k < dg; ++k)
            s0 += bf2f(p[col[rs + k] * 64 + lane]);

        float sum = ((s0 + s1) + (s2 + s3)) + ((s4 + s5) + (s6 + s7));
        float mean = sum / fmaxf((float)dg, 1.0f);
        float h2 = fmaxf(mean + bias + bf2f(q[node * 64 + lane]), 0.f);

        float p0 = h2 * wo0, p1 = h2 * wo1;
#pragma unroll
        for (int off = 32; off > 0; off >>= 1) {
            p0 += __shfl_down(p0, off, 64);
            p1 += __shfl_down(p1, off, 64);
        }
        if (lane == 0) {
            int g = batch[node];
            atomicAdd(&gsum[g * 2 + 0], p0);
            atomicAdd(&gsum[g * 2 + 1], p1);
        }
    }
}

// ---------------- finalize: out = gsum/cnt + bout ----------------
__global__ __launch_bounds__(256) void finalize_kernel(
    const float* __restrict__ gsum, const int* __restrict__ gstart,
    const float* __restrict__ bout, float* __restrict__ out)
{
    int g = blockIdx.x * 256 + threadIdx.x;
    if (g >= N_GRAPHS) return;
    int cnt = gstart[g + 1] - gstart[g];
    float inv = 1.0f / fmaxf((float)cnt, 1.0f);
    out[g * 2 + 0] = gsum[g * 2 + 0] * inv + bout[0];
    out[g * 2 + 1] = gsum[g * 2 + 1] * inv + bout[1];
}

extern "C" void kernel_launch(void* const* d_in, const int* in_sizes, int n_in,
                              void* d_out, int out_size, void* d_ws, size_t ws_size,
                              hipStream_t stream) {
    const int*   x    = (const int*)  d_in[0];
    const int*   ei   = (const int*)  d_in[1];
    const int*   batch= (const int*)  d_in[2];
    const float* emb  = (const float*)d_in[3];
    const float* W1l  = (const float*)d_in[4];
    const float* b1   = (const float*)d_in[5];
    const float* W1r  = (const float*)d_in[6];
    const float* W2l  = (const float*)d_in[7];
    const float* b2   = (const float*)d_in[8];
    const float* W2r  = (const float*)d_in[9];
    const float* Wout = (const float*)d_in[10];
    const float* bout = (const float*)d_in[11];
    float* out = (float*)d_out;

    const int* src = ei;
    const int* dst = ei + N_EDGES;

    char* ws = (char*)d_ws;
    size_t off = 0;
    __hip_bfloat16* p16 = (__hip_bfloat16*)(ws + off); off += (size_t)N_NODES * 64 * 2; // 12.8 MB
    __hip_bfloat16* q16 = (__hip_bfloat16*)(ws + off); off += (size_t)N_NODES * 64 * 2; // 12.8 MB
    float*    embW1l = (float*)   (ws + off); off += (size_t)VOCAB * 64 * 4;
    float*    embW1r = (float*)   (ws + off); off += (size_t)VOCAB * 64 * 4;
    int*      rowst  = (int*)     (ws + off); off += (size_t)N_NODES * 4;
    int*      deg    = (int*)     (ws + off); off += (size_t)N_NODES * 4;
    int*      col    = (int*)     (ws + off); off += (size_t)NBK * CAP * 4;   // 6.4 MB
    unsigned* edge8  = (unsigned*)(ws + off); off += (size_t)NBK * CAP * 4;   // 6.4 MB
    int*      cursor = (int*)     (ws + off); off += (size_t)NBK * 4;
    int*      gstart = (int*)     (ws + off); off += (size_t)(N_GRAPHS + 1) * 4;
    float*    gsum   = (float*)   (ws + off); off += (size_t)N_GRAPHS * 2 * 4;

    init_kernel<<<16, 256, 0, stream>>>(cursor, gsum);
    precompute_kernel<<<32, 256, 0, stream>>>(emb, W1l, W1r, embW1l, embW1r);
    scatter_kernel<<<SCAT_BLOCKS, 256, 0, stream>>>(src, dst, cursor, edge8);
    gstart_kernel<<<(N_NODES + 255) / 256, 256, 0, stream>>>(batch, gstart);
    csr_kernel<<<NBK, 256, 0, stream>>>(edge8, cursor, rowst, deg, col);
    sage1_kernel<<<N_NODES / (4 * S1_NPW), 256, 0, stream>>>(
        x, embW1l, embW1r, b1, rowst, deg, col, W2l, W2r, p16, q16);
    sage2_kernel<<<N_NODES / (4 * S2_NPW), 256, 0, stream>>>(
        (const unsigned short*)p16, (const unsigned short*)q16,
        rowst, deg, col, b2, Wout, batch, gsum);
    finalize_kernel<<<(N_GRAPHS + 255) / 256, 256, 0, stream>>>(gsum, gstart, bout, out);
}

// Round 8
// 230.618 us; speedup vs baseline: 1.8549x; 1.0756x over previous
//
#include <hip/hip_runtime.h>
#include <hip/hip_bf16.h>

#define N_NODES 100000
#define N_EDGES 1000000
#define EMB 64
#define HID 64
#define VOCAB 128
#define N_GRAPHS 2048

#define CBUCKET 1024                                   // nodes per bucket
#define NBK ((N_NODES + CBUCKET - 1) / CBUCKET)        // 98
#define CAP 16384                                      // slots per bucket (E[cnt]=10204)
#define CHUNK 4096
#define SCAT_BLOCKS ((N_EDGES + CHUNK - 1) / CHUNK)    // 245

#define BCASTF(v, l) __int_as_float(__builtin_amdgcn_readlane(__float_as_int(v), (l)))

typedef __attribute__((ext_vector_type(8))) short short8;
typedef __attribute__((ext_vector_type(4))) float f32x4;

__device__ __forceinline__ float bf2f(unsigned short u) {
    return __uint_as_float((unsigned)u << 16);
}
__device__ __forceinline__ unsigned short f2bf(float f) {
    return __bfloat16_as_ushort(__float2bfloat16(f));
}

// ---- init: cursor[k] = k*CAP, gsum = 0 ----
__global__ __launch_bounds__(256) void init_kernel(
    int* __restrict__ cursor, float* __restrict__ gsum)
{
    int t = blockIdx.x * 256 + threadIdx.x;
    if (t < NBK) cursor[t] = t * CAP;
    if (t < N_GRAPHS * 2) gsum[t] = 0.f;
}

// ---- precompute embW1l = emb@W1l, embW1r = emb@W1r (128x64 fp32)
//      + pack W2cat = [W2l | W2r] (64x128) into MFMA B-fragment order bf16.
// 32 blocks x 256 = 8192 threads = exactly 8192 w2frag elements.
__global__ __launch_bounds__(256) void precompute_kernel(
    const float* __restrict__ emb, const float* __restrict__ W1l,
    const float* __restrict__ W1r,
    const float* __restrict__ W2l, const float* __restrict__ W2r,
    float* __restrict__ embW1l, float* __restrict__ embW1r,
    unsigned short* __restrict__ w2frag)
{
    int wave = threadIdx.x >> 6, lane = threadIdx.x & 63;
    int v = blockIdx.x * 4 + wave;
    if (v < VOCAB) {
        float er = emb[v * 64 + lane];       // lane = d
        float al = 0.f, ar = 0.f;
#pragma unroll 8
        for (int d = 0; d < 64; ++d) {
            float e = BCASTF(er, d);
            al += e * W1l[d * 64 + lane];    // lane = o, L1-hot
            ar += e * W1r[d * 64 + lane];
        }
        embW1l[v * 64 + lane] = al;
        embW1r[v * 64 + lane] = ar;
    }
    // B-fragment packing: g = t*1024 + h*512 + l*8 + j
    // holds W2cat[k = h*32 + (l>>4)*8 + j][n = t*16 + (l&15)]
    int g = blockIdx.x * 256 + threadIdx.x;
    int j = g & 7, l = (g >> 3) & 63, h = (g >> 9) & 1, tt = g >> 10;
    int k = h * 32 + ((l >> 4) * 8) + j;
    int n = tt * 16 + (l & 15);
    float w = (n < 64) ? W2l[k * 64 + n] : W2r[k * 64 + (n - 64)];
    w2frag[g] = f2bf(w);
}

// ---- scatter: LDS-staged chunk, per-(block,bucket) run reservation ----
__global__ __launch_bounds__(256) void scatter_kernel(
    const int* __restrict__ src, const int* __restrict__ dst,
    int* __restrict__ cursor, unsigned* __restrict__ edge8)
{
    __shared__ unsigned earr[CHUNK];        // 16 KB packed payload
    __shared__ unsigned char karr[CHUNK];   // 4 KB bucket key
    __shared__ int bcnt[NBK];
    __shared__ int bbase[NBK];
    int t = threadIdx.x;
    if (t < NBK) bcnt[t] = 0;
    __syncthreads();
    int e0 = blockIdx.x * CHUNK;
    int n = min(e0 + CHUNK, N_EDGES) - e0;
    for (int i = t; i < n; i += 256) {
        int d = dst[e0 + i];
        int s = src[e0 + i];
        int k = d >> 10;
        earr[i] = (unsigned)s | ((unsigned)(d & 1023) << 17);   // src < 2^17
        karr[i] = (unsigned char)k;
        atomicAdd(&bcnt[k], 1);
    }
    __syncthreads();
    if (t < NBK) {
        int c = bcnt[t];
        bbase[t] = c ? atomicAdd(&cursor[t], c) : 0;
        bcnt[t] = 0;                        // reuse as local cursor
    }
    __syncthreads();
    for (int i = t; i < n; i += 256) {
        int k = karr[i];
        int off = atomicAdd(&bcnt[k], 1);
        edge8[bbase[k] + off] = earr[i];    // dense single-writer runs
    }
}

// ---- per-bucket CSR build (rowstart/deg/col), dense writes ------
__global__ __launch_bounds__(256) void csr_kernel(
    const unsigned* __restrict__ edge8, const int* __restrict__ cursor,
    int* __restrict__ row_start, int* __restrict__ deg, int* __restrict__ col)
{
    __shared__ int cnt[CBUCKET];
    __shared__ int ssum[256];
    int b = blockIdx.x;                   // NBK blocks
    int t = threadIdx.x;
    int lo = b * CAP, hi = cursor[b];     // cursor holds final fill level
    for (int i = t; i < CBUCKET; i += 256) cnt[i] = 0;
    __syncthreads();
    for (int i = lo + t; i < hi; i += 256)
        atomicAdd(&cnt[edge8[i] >> 17], 1);
    __syncthreads();
    int v[4]; int sum = 0;
#pragma unroll
    for (int i = 0; i < 4; ++i) { v[i] = cnt[t * 4 + i]; sum += v[i]; }
    ssum[t] = sum;
    __syncthreads();
    for (int off = 1; off < 256; off <<= 1) {
        int tmp = (t >= off) ? ssum[t - off] : 0;
        __syncthreads();
        ssum[t] += tmp;
        __syncthreads();
    }
    int run = ssum[t] - sum;
    int ex0 = run, ex1 = ex0 + v[0], ex2 = ex1 + v[1], ex3 = ex2 + v[2];
    int node = b * CBUCKET + t * 4;
    if (node + 3 < N_NODES) {
        *(int4*)&row_start[node] = make_int4(lo + ex0, lo + ex1, lo + ex2, lo + ex3);
        *(int4*)&deg[node]       = make_int4(v[0], v[1], v[2], v[3]);
    } else {
        int ex[4] = {ex0, ex1, ex2, ex3};
        for (int i = 0; i < 4; ++i)
            if (node + i < N_NODES) { row_start[node + i] = lo + ex[i]; deg[node + i] = v[i]; }
    }
    cnt[t * 4 + 0] = ex0; cnt[t * 4 + 1] = ex1;       // reuse as cursors
    cnt[t * 4 + 2] = ex2; cnt[t * 4 + 3] = ex3;
    __syncthreads();
    for (int i = lo + t; i < hi; i += 256) {
        unsigned e = edge8[i];
        int slot = atomicAdd(&cnt[e >> 17], 1);
        col[lo + slot] = (int)(e & 0x1FFFF);          // dense ~40 KB window
    }
}

// ---- graph boundaries (batch sorted) -------------------------------------
__global__ __launch_bounds__(256) void gstart_kernel(
    const int* __restrict__ batch, int* __restrict__ gstart)
{
    int i = blockIdx.x * 256 + threadIdx.x;
    if (i >= N_NODES) return;
    int bg = batch[i];
    int bp = (i == 0) ? -1 : batch[i - 1];
    for (int g = bp + 1; g <= bg; ++g) gstart[g] = i;
    if (i == N_NODES - 1)
        for (int g = bg + 1; g <= N_GRAPHS; ++g) gstart[g] = N_NODES;
}

// ---- layer 1 (lean): h1 = relu(mean_j(embW1l[x_j]) + b1 + embW1r[x_i]),
//      stored bf16 (identical precision to bf16-MFMA A-operand conversion)
#define S1_NPW 8
__global__ __launch_bounds__(256) void sage1_kernel(
    const int* __restrict__ x, const float* __restrict__ embW1l,
    const float* __restrict__ embW1r, const float* __restrict__ b1,
    const int* __restrict__ row_start, const int* __restrict__ deg,
    const int* __restrict__ col, unsigned short* __restrict__ h1b)
{
    __shared__ float elds[VOCAB * 64];      // 32 KB -> 5 blocks/CU
    int t = threadIdx.x;
    for (int i = t * 4; i < VOCAB * 64; i += 1024)
        *(float4*)&elds[i] = *(const float4*)&embW1l[i];
    __syncthreads();

    int wave = t >> 6, lane = t & 63;
    int base_node = (blockIdx.x * 4 + wave) * S1_NPW;   // 3125*32 = 100000 exact
    float bias = b1[lane];

    for (int n = 0; n < S1_NPW; ++n) {
        int node = base_node + n;
        int rs = row_start[node];
        int dg = deg[node];
        int xn = x[node];
        float self = embW1r[xn * 64 + lane];            // 32 KB table, L2-hot
        int cidx = (lane < dg) ? col[rs + lane] : 0;
        int xv = (lane < dg) ? x[cidx] : 0;
        int dgc = (dg < 64) ? dg : 64;

        float s0 = 0.f, s1 = 0.f, s2 = 0.f, s3 = 0.f;
        int j = 0;
        for (; j + 4 <= dgc; j += 4) {
            int x0 = __builtin_amdgcn_readlane(xv, j + 0);
            int x1 = __builtin_amdgcn_readlane(xv, j + 1);
            int x2 = __builtin_amdgcn_readlane(xv, j + 2);
            int x3 = __builtin_amdgcn_readlane(xv, j + 3);
            s0 += elds[x0 * 64 + lane];
            s1 += elds[x1 * 64 + lane];
            s2 += elds[x2 * 64 + lane];
            s3 += elds[x3 * 64 + lane];
        }
        for (; j < dgc; ++j) {
            int x0 = __builtin_amdgcn_readlane(xv, j);
            s0 += elds[x0 * 64 + lane];
        }
        for (int k = 64; k < dg; ++k) {                 // deg>64 tail (rare)
            int c = col[rs + k];
            s0 += elds[x[c] * 64 + lane];
        }
        float mean = ((s0 + s1) + (s2 + s3)) / fmaxf((float)dg, 1.0f);
        h1b[node * 64 + lane] = f2bf(fmaxf(mean + bias + self, 0.f));
    }
}

// ---- MFMA transform: [p|q] = h1 @ [W2l|W2r]  (M=100000, N=128, K=64) ----
// mfma_f32_16x16x32_bf16. A: m=lane&15, k=quad*8+j (b128 from h1 row).
// B: pre-packed fragments (w2frag). C/D: col=lane&15, row=quad*4+reg.
__global__ __launch_bounds__(256) void mfma_transform_kernel(
    const unsigned short* __restrict__ h1b,
    const unsigned short* __restrict__ w2frag,
    unsigned short* __restrict__ p16, unsigned short* __restrict__ q16)
{
    int wave = threadIdx.x >> 6, lane = threadIdx.x & 63;
    int base16 = blockIdx.x * 64 + wave * 16;
    if (base16 >= N_NODES) return;                      // tail waves only
    int m = lane & 15, quad = lane >> 4;

    const unsigned short* arow = h1b + (base16 + m) * 64 + quad * 8;
    short8 a0 = *(const short8*)(arow);                 // k = 0..31
    short8 a1 = *(const short8*)(arow + 32);            // k = 32..63

#pragma unroll
    for (int tt = 0; tt < 8; ++tt) {                    // 8 output tiles of 16
        short8 b0 = *(const short8*)(w2frag + (tt * 1024 + 0)   + lane * 8);
        short8 b1 = *(const short8*)(w2frag + (tt * 1024 + 512) + lane * 8);
        f32x4 acc = {0.f, 0.f, 0.f, 0.f};
        acc = __builtin_amdgcn_mfma_f32_16x16x32_bf16(a0, b0, acc, 0, 0, 0);
        acc = __builtin_amdgcn_mfma_f32_16x16x32_bf16(a1, b1, acc, 0, 0, 0);
        int o = tt * 16 + m;
        unsigned short* dstbuf = (o < 64) ? p16 : q16;
        int oc = o & 63;
#pragma unroll
        for (int i = 0; i < 4; ++i) {
            int node = base16 + quad * 4 + i;
            dstbuf[node * 64 + oc] = f2bf(acc[i]);
        }
    }
}

// ---- lean gather: h2 = relu(mean_j p_j + b2 + q_i); gsum[g] += h2@Wout ----
#define S2_NPW 8
__global__ __launch_bounds__(256, 8) void sage2_kernel(
    const unsigned short* __restrict__ p, const unsigned short* __restrict__ q,
    const int* __restrict__ row_start, const int* __restrict__ deg,
    const int* __restrict__ col, const float* __restrict__ b2,
    const float* __restrict__ Wout, const int* __restrict__ batch,
    float* __restrict__ gsum)
{
    int t = threadIdx.x;
    int wave = t >> 6, lane = t & 63;
    int base_node = (blockIdx.x * 4 + wave) * S2_NPW;   // exact cover
    float bias = b2[lane];
    float wo0 = Wout[lane * 2 + 0], wo1 = Wout[lane * 2 + 1];

    for (int n = 0; n < S2_NPW; ++n) {
        int node = base_node + n;
        int rs = row_start[node];       // wave-uniform -> scalar
        int dg = deg[node];
        int cidx = (lane < dg) ? col[rs + lane] : 0;
        int dgc = (dg < 64) ? dg : 64;

        float s0 = 0.f, s1 = 0.f, s2 = 0.f, s3 = 0.f,
              s4 = 0.f, s5 = 0.f, s6 = 0.f, s7 = 0.f;
        int j = 0;
        for (; j + 8 <= dgc; j += 8) {
            int i0 = __builtin_amdgcn_readlane(cidx, j + 0);
            int i1 = __builtin_amdgcn_readlane(cidx, j + 1);
            int i2 = __builtin_amdgcn_readlane(cidx, j + 2);
            int i3 = __builtin_amdgcn_readlane(cidx, j + 3);
            int i4 = __builtin_amdgcn_readlane(cidx, j + 4);
            int i5 = __builtin_amdgcn_readlane(cidx, j + 5);
            int i6 = __builtin_amdgcn_readlane(cidx, j + 6);
            int i7 = __builtin_amdgcn_readlane(cidx, j + 7);
            s0 += bf2f(p[i0 * 64 + lane]);  s1 += bf2f(p[i1 * 64 + lane]);
            s2 += bf2f(p[i2 * 64 + lane]);  s3 += bf2f(p[i3 * 64 + lane]);
            s4 += bf2f(p[i4 * 64 + lane]);  s5 += bf2f(p[i5 * 64 + lane]);
            s6 += bf2f(p[i6 * 64 + lane]);  s7 += bf2f(p[i7 * 64 + lane]);
        }
        for (; j + 4 <= dgc; j += 4) {
            int i0 = __builtin_amdgcn_readlane(cidx, j + 0);
            int i1 = __builtin_amdgcn_readlane(cidx, j + 1);
            int i2 = __builtin_amdgcn_readlane(cidx, j + 2);
            int i3 = __builtin_amdgcn_readlane(cidx, j + 3);
            s0 += bf2f(p[i0 * 64 + lane]);  s1 += bf2f(p[i1 * 64 + lane]);
            s2 += bf2f(p[i2 * 64 + lane]);  s3 += bf2f(p[i3 * 64 + lane]);
        }
        for (; j < dgc; ++j) {
            int i0 = __builtin_amdgcn_readlane(cidx, j);
            s0 += bf2f(p[i0 * 64 + lane]);
        }
        for (int k = 64; k < dg; ++k)
            s0 += bf2f(p[col[rs + k] * 64 + lane]);

        float sum = ((s0 + s1) + (s2 + s3)) + ((s4 + s5) + (s6 + s7));
        float mean = sum / fmaxf((float)dg, 1.0f);
        float h2 = fmaxf(mean + bias + bf2f(q[node * 64 + lane]), 0.f);

        float p0 = h2 * wo0, p1 = h2 * wo1;
#pragma unroll
        for (int off = 32; off > 0; off >>= 1) {
            p0 += __shfl_down(p0, off, 64);
            p1 += __shfl_down(p1, off, 64);
        }
        if (lane == 0) {
            int g = batch[node];
            atomicAdd(&gsum[g * 2 + 0], p0);
            atomicAdd(&gsum[g * 2 + 1], p1);
        }
    }
}

// ---------------- finalize: out = gsum/cnt + bout ----------------
__global__ __launch_bounds__(256) void finalize_kernel(
    const float* __restrict__ gsum, const int* __restrict__ gstart,
    const float* __restrict__ bout, float* __restrict__ out)
{
    int g = blockIdx.x * 256 + threadIdx.x;
    if (g >= N_GRAPHS) return;
    int cnt = gstart[g + 1] - gstart[g];
    float inv = 1.0f / fmaxf((float)cnt, 1.0f);
    out[g * 2 + 0] = gsum[g * 2 + 0] * inv + bout[0];
    out[g * 2 + 1] = gsum[g * 2 + 1] * inv + bout[1];
}

extern "C" void kernel_launch(void* const* d_in, const int* in_sizes, int n_in,
                              void* d_out, int out_size, void* d_ws, size_t ws_size,
                              hipStream_t stream) {
    const int*   x    = (const int*)  d_in[0];
    const int*   ei   = (const int*)  d_in[1];
    const int*   batch= (const int*)  d_in[2];
    const float* emb  = (const float*)d_in[3];
    const float* W1l  = (const float*)d_in[4];
    const float* b1   = (const float*)d_in[5];
    const float* W1r  = (const float*)d_in[6];
    const float* W2l  = (const float*)d_in[7];
    const float* b2   = (const float*)d_in[8];
    const float* W2r  = (const float*)d_in[9];
    const float* Wout = (const float*)d_in[10];
    const float* bout = (const float*)d_in[11];
    float* out = (float*)d_out;

    const int* src = ei;
    const int* dst = ei + N_EDGES;

    char* ws = (char*)d_ws;
    size_t off = 0;
    unsigned short* p16    = (unsigned short*)(ws + off); off += (size_t)N_NODES * 64 * 2;
    unsigned short* q16    = (unsigned short*)(ws + off); off += (size_t)N_NODES * 64 * 2;
    unsigned short* h1b    = (unsigned short*)(ws + off); off += (size_t)N_NODES * 64 * 2;
    unsigned short* w2frag = (unsigned short*)(ws + off); off += (size_t)8192 * 2;
    float*    embW1l = (float*)   (ws + off); off += (size_t)VOCAB * 64 * 4;
    float*    embW1r = (float*)   (ws + off); off += (size_t)VOCAB * 64 * 4;
    int*      rowst  = (int*)     (ws + off); off += (size_t)N_NODES * 4;
    int*      deg    = (int*)     (ws + off); off += (size_t)N_NODES * 4;
    int*      col    = (int*)     (ws + off); off += (size_t)NBK * CAP * 4;
    unsigned* edge8  = (unsigned*)(ws + off); off += (size_t)NBK * CAP * 4;
    int*      cursor = (int*)     (ws + off); off += (size_t)NBK * 4;
    int*      gstart = (int*)     (ws + off); off += (size_t)(N_GRAPHS + 1) * 4;
    float*    gsum   = (float*)   (ws + off); off += (size_t)N_GRAPHS * 2 * 4;

    init_kernel<<<16, 256, 0, stream>>>(cursor, gsum);
    precompute_kernel<<<32, 256, 0, stream>>>(emb, W1l, W1r, W2l, W2r,
                                              embW1l, embW1r, w2frag);
    scatter_kernel<<<SCAT_BLOCKS, 256, 0, stream>>>(src, dst, cursor, edge8);
    gstart_kernel<<<(N_NODES + 255) / 256, 256, 0, stream>>>(batch, gstart);
    csr_kernel<<<NBK, 256, 0, stream>>>(edge8, cursor, rowst, deg, col);
    sage1_kernel<<<N_NODES / (4 * S1_NPW), 256, 0, stream>>>(
        x, embW1l, embW1r, b1, rowst, deg, col, h1b);
    mfma_transform_kernel<<<(N_NODES + 63) / 64, 256, 0, stream>>>(
        h1b, w2frag, p16, q16);
    sage2_kernel<<<N_NODES / (4 * S2_NPW), 256, 0, stream>>>(
        p16, q16, rowst, deg, col, b2, Wout, batch, gsum);
    finalize_kernel<<<(N_GRAPHS + 255) / 256, 256, 0, stream>>>(gsum, gstart, bout, out);
}